// Round 4
// baseline (643.404 us; speedup 1.0000x reference)
//
#include <hip/hip_runtime.h>
#include <hip/hip_bf16.h>
#include <math.h>

typedef short short8 __attribute__((ext_vector_type(8)));
typedef float f32x4 __attribute__((ext_vector_type(4)));

__device__ __forceinline__ unsigned short f2bf(float x) {
    unsigned u = __float_as_uint(x);
    u += 0x7FFF + ((u >> 16) & 1);   // RNE
    return (unsigned short)(u >> 16);
}
__device__ __forceinline__ float bf2f(unsigned short h) {
    return __uint_as_float(((unsigned)h) << 16);
}

// split 8 fp32 -> bf16 hi (RNE) + bf16 lo (residual), packed as short8
__device__ __forceinline__ void cvt8(const float4 a, const float4 b,
                                     short8& hi, short8& lo) {
    float f[8] = {a.x, a.y, a.z, a.w, b.x, b.y, b.z, b.w};
    unsigned hu[4], lu[4];
#pragma unroll
    for (int p = 0; p < 4; ++p) {
        __hip_bfloat162 h = __float22bfloat162_rn(float2{f[2 * p], f[2 * p + 1]});
        hu[p] = *(unsigned*)&h;
        float r0 = f[2 * p]     - __uint_as_float(hu[p] << 16);
        float r1 = f[2 * p + 1] - __uint_as_float(hu[p] & 0xFFFF0000u);
        __hip_bfloat162 lo2 = __float22bfloat162_rn(float2{r0, r1});
        lu[p] = *(unsigned*)&lo2;
    }
    hi = *(short8*)hu;
    lo = *(short8*)lu;
}

__device__ __forceinline__ float tanh10(float y) {
    float e = __expf(2.f * y);
    return 10.f * (e - 1.f) / (e + 1.f);
}

// ---------------------------------------------------------------------------
// K0: prep — Wt (fp32 transpose) + bf16 hi/lo split of W (row-major d x k)
// ---------------------------------------------------------------------------
__global__ __launch_bounds__(256) void k_prep(const float* __restrict__ W,
                                              float* __restrict__ Wt,
                                              unsigned short* __restrict__ Whi,
                                              unsigned short* __restrict__ Wlo) {
    int d = blockIdx.x, k = threadIdx.x;
    float w = W[d * 256 + k];
    Wt[k * 256 + d] = w;
    unsigned short hi = f2bf(w);
    Whi[d * 256 + k] = hi;
    Wlo[d * 256 + k] = f2bf(w - bf2f(hi));
}

// ---------------------------------------------------------------------------
// K1: node projection, 8-way acc split
// ---------------------------------------------------------------------------
__global__ __launch_bounds__(256) void k_node_proj(const float* __restrict__ nodes,
                                                   const float* __restrict__ Wt,
                                                   const float* __restrict__ bias,
                                                   float* __restrict__ np_) {
    int row = blockIdx.x;
    int d = threadIdx.x;
    __shared__ float xl[256];
    xl[d] = nodes[row * 256 + d];
    __syncthreads();
    float a[8] = {0.f, 0.f, 0.f, 0.f, 0.f, 0.f, 0.f, 0.f};
#pragma unroll 4
    for (int k = 0; k < 256; k += 8) {
#pragma unroll
        for (int q = 0; q < 8; ++q)
            a[q] = fmaf(xl[k + q], Wt[(k + q) * 256 + d], a[q]);
    }
    np_[row * 256 + d] =
        bias[d] + ((a[0] + a[1]) + (a[2] + a[3])) + ((a[4] + a[5]) + (a[6] + a[7]));
}

// ---------------------------------------------------------------------------
// K2: MFMA edge scores — NO LDS in the K-loop, no barriers.
// Block = 64 edges (same b,i; consecutive j) x 256 dims (all 8 heads).
// 4 waves: wm=(w&1)*32 edges, wn=(w>>1)*128 dims; per wave mt=2 x nt=8 tiles.
// A (edges fp32) loaded straight into the MFMA A-fragment pattern
// (row=lane&15, k=(lane>>4)*8), converted in regs to split-bf16; register
// prefetch one chunk ahead stays in flight (no barrier to drain vmcnt).
// B (pre-split bf16 W) loaded per chunk from global — L1/L2-hot.
// acc = Ah*Bh + Ah*Bl + Al*Bh (fp32).
// ---------------------------------------------------------------------------
__global__ __launch_bounds__(256) void k_edge_mfma(const float* __restrict__ edges,
                                                   const unsigned short* __restrict__ Whi,
                                                   const unsigned short* __restrict__ Wlo,
                                                   const float* __restrict__ bias,
                                                   const float* __restrict__ np_,
                                                   float* __restrict__ attn) {
    __shared__ float sc[8][64];

    const int t = threadIdx.x;
    const int w = t >> 6, l = t & 63;
    const int col = l & 15, g = l >> 4;
    const int m0 = blockIdx.x * 64;        // first edge flat index
    const int bb = m0 >> 16;
    const int ii = (m0 >> 8) & 255;
    const int j0 = m0 & 255;
    const int wm = (w & 1) * 32;
    const int wn = (w >> 1) * 128;

    f32x4 acc[2][8];
#pragma unroll
    for (int mt = 0; mt < 2; ++mt)
#pragma unroll
        for (int nt = 0; nt < 8; ++nt) acc[mt][nt] = (f32x4){0.f, 0.f, 0.f, 0.f};

    // A source: lane reads 8 consecutive k at row (m0+wm+mt*16+col)
    const float* arow = edges + (size_t)(m0 + wm + col) * 256 + g * 8;
    // B source rows
    const unsigned short* bh0 = Whi + (size_t)(wn + col) * 256 + g * 8;
    const unsigned short* bl0 = Wlo + (size_t)(wn + col) * 256 + g * 8;

    float4 ac[2][2], an[2][2];
#pragma unroll
    for (int mt = 0; mt < 2; ++mt) {
        ac[mt][0] = *(const float4*)(arow + mt * 4096);
        ac[mt][1] = *(const float4*)(arow + mt * 4096 + 4);
    }

    for (int kc = 0; kc < 8; ++kc) {
        // prefetch next A chunk (stays in flight across the MFMAs below)
        if (kc < 7) {
#pragma unroll
            for (int mt = 0; mt < 2; ++mt) {
                an[mt][0] = *(const float4*)(arow + mt * 4096 + (kc + 1) * 32);
                an[mt][1] = *(const float4*)(arow + mt * 4096 + (kc + 1) * 32 + 4);
            }
        }
        // B fragments for this chunk (16 x dwordx4, L1/L2-hot)
        short8 Bh[8], Bl[8];
#pragma unroll
        for (int nt = 0; nt < 8; ++nt) {
            Bh[nt] = *(const short8*)(bh0 + (size_t)nt * 4096 + kc * 32);
            Bl[nt] = *(const short8*)(bl0 + (size_t)nt * 4096 + kc * 32);
        }
        // convert current A regs to split-bf16 fragments
        short8 Ah[2], Al[2];
#pragma unroll
        for (int mt = 0; mt < 2; ++mt) cvt8(ac[mt][0], ac[mt][1], Ah[mt], Al[mt]);
        // MFMA
#pragma unroll
        for (int nt = 0; nt < 8; ++nt)
#pragma unroll
            for (int mt = 0; mt < 2; ++mt) {
                acc[mt][nt] = __builtin_amdgcn_mfma_f32_16x16x32_bf16(Ah[mt], Bh[nt], acc[mt][nt], 0, 0, 0);
                acc[mt][nt] = __builtin_amdgcn_mfma_f32_16x16x32_bf16(Ah[mt], Bl[nt], acc[mt][nt], 0, 0, 0);
                acc[mt][nt] = __builtin_amdgcn_mfma_f32_16x16x32_bf16(Al[mt], Bh[nt], acc[mt][nt], 0, 0, 0);
            }
#pragma unroll
        for (int mt = 0; mt < 2; ++mt) {
            ac[mt][0] = an[mt][0];
            ac[mt][1] = an[mt][1];
        }
    }

    // ---- epilogue: per head h: score = sum_{d in head} (p+ni_d)(p+nj_d)
    const float isq = 0.17677669529663687f;  // 1/sqrt(32)
    float bv[8], nv[8];
    const float* npi = np_ + (size_t)(bb * 256 + ii) * 256 + wn;
#pragma unroll
    for (int nt = 0; nt < 8; ++nt) {
        bv[nt] = bias[wn + nt * 16 + col];
        nv[nt] = npi[nt * 16 + col];
    }
#pragma unroll
    for (int mt = 0; mt < 2; ++mt) {
#pragma unroll
        for (int r = 0; r < 4; ++r) {
            int el = wm + mt * 16 + g * 4 + r;   // 0..63 within tile
            int j = j0 + el;
            const float* npj = np_ + (size_t)(bb * 256 + j) * 256 + wn;
            float s[4] = {0.f, 0.f, 0.f, 0.f};
#pragma unroll
            for (int nt = 0; nt < 8; ++nt) {
                float p = acc[mt][nt][r] + bv[nt];
                s[nt >> 1] += (p + nv[nt]) * (p + npj[nt * 16 + col]);
            }
#pragma unroll
            for (int m = 1; m < 16; m <<= 1) {
#pragma unroll
                for (int q = 0; q < 4; ++q) s[q] += __shfl_xor(s[q], m, 64);
            }
            if (col == 0) {
#pragma unroll
                for (int q = 0; q < 4; ++q)
                    sc[(wn >> 5) + q][el] = tanh10(s[q] * isq);
            }
        }
    }
    __syncthreads();
    if (t < 128) {
        int hl = t >> 4, q = t & 15;
        float4 v = *(float4*)&sc[hl][q * 4];
        *(float4*)(attn + (((size_t)(bb * 8 + hl) * 256 + ii) << 8) + j0 + q * 4) = v;
    }
}

// ---------------------------------------------------------------------------
// K3: fused softmax + attn@np + output projection. Block per (b,i).
// Reads RAW scores from attn region, softmaxes (writes softmaxed attn back
// to global), then out = proj(attn_row @ np).
// ---------------------------------------------------------------------------
__global__ __launch_bounds__(256) void k_smout(float* __restrict__ attn,
                                               const float* __restrict__ np_,
                                               const float* __restrict__ Wt,
                                               const float* __restrict__ bias,
                                               float* __restrict__ out) {
    int bi = blockIdx.x;
    int bb = bi >> 8, ii = bi & 255;
    int t = threadIdx.x;
    int w = t >> 6, l = t & 63;
    __shared__ float at[8 * 256];
    __shared__ float xl[256];
    // load raw scores (8 rows x 256)
#pragma unroll
    for (int s = 0; s < 2; ++s) {
        int idx = t + s * 256;
        int h = idx >> 6, q = idx & 63;
        ((float4*)at)[idx] =
            ((const float4*)(attn + ((size_t)(bb * 8 + h) * 256 + ii) * 256))[q];
    }
    __syncthreads();
    // softmax: wave w handles rows 2w, 2w+1
#pragma unroll
    for (int rr = 0; rr < 2; ++rr) {
        int h = 2 * w + rr;
        float4 v = ((float4*)(at + h * 256))[l];
        float m = fmaxf(fmaxf(v.x, v.y), fmaxf(v.z, v.w));
#pragma unroll
        for (int s = 1; s < 64; s <<= 1) m = fmaxf(m, __shfl_xor(m, s, 64));
        v.x = __expf(v.x - m); v.y = __expf(v.y - m);
        v.z = __expf(v.z - m); v.w = __expf(v.w - m);
        float sum = v.x + v.y + v.z + v.w;
#pragma unroll
        for (int s = 1; s < 64; s <<= 1) sum += __shfl_xor(sum, s, 64);
        float inv = 1.f / sum;
        v.x *= inv; v.y *= inv; v.z *= inv; v.w *= inv;
        ((float4*)(at + h * 256))[l] = v;
        ((float4*)(attn + ((size_t)(bb * 8 + h) * 256 + ii) * 256))[l] = v;
    }
    __syncthreads();
    // attn_row @ np
    int d = t;
    int h = d >> 5;
    const float* npb = np_ + (size_t)bb * 65536 + d;
    const float* ath = at + h * 256;
    float a[8] = {0.f, 0.f, 0.f, 0.f, 0.f, 0.f, 0.f, 0.f};
#pragma unroll 2
    for (int j = 0; j < 256; j += 8) {
#pragma unroll
        for (int q = 0; q < 8; ++q)
            a[q] = fmaf(ath[j + q], npb[(size_t)(j + q) * 256], a[q]);
    }
    xl[d] = ((a[0] + a[1]) + (a[2] + a[3])) + ((a[4] + a[5]) + (a[6] + a[7]));
    __syncthreads();
    // output projection
    float c[8] = {bias[d], 0.f, 0.f, 0.f, 0.f, 0.f, 0.f, 0.f};
#pragma unroll 2
    for (int k = 0; k < 256; k += 8) {
#pragma unroll
        for (int q = 0; q < 8; ++q)
            c[q] = fmaf(xl[k + q], Wt[(k + q) * 256 + d], c[q]);
    }
    out[bi * 256 + d] =
        ((c[0] + c[1]) + (c[2] + c[3])) + ((c[4] + c[5]) + (c[6] + c[7]));
}

// ---------------------------------------------------------------------------
extern "C" void kernel_launch(void* const* d_in, const int* in_sizes, int n_in,
                              void* d_out, int out_size, void* d_ws, size_t ws_size,
                              hipStream_t stream) {
    (void)in_sizes; (void)n_in; (void)out_size; (void)ws_size;
    const float* nodes = (const float*)d_in[0];
    const float* edges = (const float*)d_in[1];
    const float* W     = (const float*)d_in[2];
    const float* bias  = (const float*)d_in[3];

    float* out  = (float*)d_out;            // (4,256,256)
    float* attn = out + 262144;             // (4,8,256,256)

    float* np_ = (float*)d_ws;              // 262144 floats
    float* Wt  = np_ + 262144;              // 65536 floats
    unsigned short* Whi = (unsigned short*)(Wt + 65536);  // 65536 bf16
    unsigned short* Wlo = Whi + 65536;                    // 65536 bf16

    hipLaunchKernelGGL(k_prep,      dim3(256),  dim3(256), 0, stream, W, Wt, Whi, Wlo);
    hipLaunchKernelGGL(k_node_proj, dim3(1024), dim3(256), 0, stream, nodes, Wt, bias, np_);
    hipLaunchKernelGGL(k_edge_mfma, dim3(4096), dim3(256), 0, stream, edges, Whi, Wlo, bias, np_, attn);
    hipLaunchKernelGGL(k_smout,     dim3(1024), dim3(256), 0, stream, attn, np_, Wt, bias, out);
}